// Round 8
// baseline (236.011 us; speedup 1.0000x reference)
//
#include <hip/hip_runtime.h>

typedef __attribute__((ext_vector_type(8))) short short8;
typedef __attribute__((ext_vector_type(4))) short short4v;
typedef __attribute__((ext_vector_type(4))) float floatx4;
typedef __attribute__((ext_vector_type(16))) float floatx16;
typedef __attribute__((ext_vector_type(2))) int iv2;

#define GLOBAL_AS __attribute__((address_space(1)))
#define LDS_AS __attribute__((address_space(3)))

__device__ __forceinline__ short f2bs(float f) {
    // RNE float -> bf16 (as short). Inputs finite here.
    union { float f; unsigned u; } v; v.f = f;
    unsigned r = v.u + 0x7fffu + ((v.u >> 16) & 1u);
    return (short)(r >> 16);
}

#if __has_builtin(__builtin_amdgcn_cvt_pk_bf16_f32)
typedef __attribute__((ext_vector_type(2))) __bf16 bf16x2;
__device__ __forceinline__ unsigned pk2(float a, float b) {
    union { bf16x2 v; unsigned u; } u;
    u.v = __builtin_amdgcn_cvt_pk_bf16_f32(a, b);
    return u.u;
}
#else
__device__ __forceinline__ unsigned pk2(float a, float b) {
    // round-half-up, non-negative finite inputs
    union { float f; unsigned u; } x, y; x.f = a; y.f = b;
    return ((y.u + 0x8000u) & 0xffff0000u) | ((x.u + 0x8000u) >> 16);
}
#endif

// ---------------- fused cast fp32 -> bf16 (x + Wq + Wk + Wv) ----------------
__global__ __launch_bounds__(256) void cast_all(const float* __restrict__ x,
                                                const float* __restrict__ Wq,
                                                const float* __restrict__ Wk,
                                                const float* __restrict__ Wv,
                                                short* __restrict__ xb,
                                                short* __restrict__ wb) {
    int b = blockIdx.x;
    int t = threadIdx.x;
    const float* src;
    short* dst;
    int idx;
    if (b < 8192) {
        src = x; dst = xb; idx = b * 1024 + t * 4;
    } else {
        int r = b - 8192;
        int wz = r >> 10;
        src = (wz == 0) ? Wq : (wz == 1) ? Wk : Wv;
        dst = wb + wz * (1 << 20);
        idx = (r & 1023) * 1024 + t * 4;
    }
    float4 v = *(const float4*)(src + idx);
    short4v o;
    o.x = f2bs(v.x); o.y = f2bs(v.y); o.z = f2bs(v.z); o.w = f2bs(v.w);
    *(short4v*)(dst + idx) = o;
}

// ---------------- QKV GEMM v3: R4-proven 128x128 dbuf, counted vmcnt ----------------
__global__ __launch_bounds__(256) void qkv_gemm(const short* __restrict__ xb,
                                                const short* __restrict__ wb,
                                                short* __restrict__ qout,
                                                short* __restrict__ kout,
                                                short* __restrict__ vtout) {
    __shared__ short As[2][128 * 64];  // [m][k], 16B chunks XOR-swizzled: slot = chunk ^ (row&7)
    __shared__ short Bs[2][128 * 64];
    const int K = 1024;
    int tid = threadIdx.x;
    int lane = tid & 63;
    int wid = tid >> 6;
    int quad = lane >> 4;
    int l16 = lane & 15;
    int wm = (wid >> 1) * 64;
    int wn = (wid & 1) * 64;
    int bm = blockIdx.x * 128;
    int bn = blockIdx.y * 128;
    const short* W = wb + (size_t)blockIdx.z * K * 1024;

    floatx4 acc[4][4];
#pragma unroll
    for (int i = 0; i < 4; i++)
#pragma unroll
        for (int j = 0; j < 4; j++) acc[i][j] = (floatx4){0.f, 0.f, 0.f, 0.f};

    int srow = tid >> 3;
    int ssw = ((tid & 7) ^ (srow & 7)) * 8;

#define STAGE_AB(cb, kk) do { \
    _Pragma("unroll") for (int l = 0; l < 4; l++) { \
        const short* g = xb + (size_t)(bm + srow + l * 32) * K + (kk) + ssw; \
        __builtin_amdgcn_global_load_lds((const GLOBAL_AS void*)g, \
            (LDS_AS void*)(&As[cb][0] + tid * 8 + l * 2048), 16, 0, 0); \
    } \
    _Pragma("unroll") for (int l = 0; l < 4; l++) { \
        const short* g = W + (size_t)(bn + srow + l * 32) * K + (kk) + ssw; \
        __builtin_amdgcn_global_load_lds((const GLOBAL_AS void*)g, \
            (LDS_AS void*)(&Bs[cb][0] + tid * 8 + l * 2048), 16, 0, 0); \
    } \
} while (0)

    STAGE_AB(0, 0);

    for (int T = 0; T < 16; T++) {
        int cur = T & 1;
        // WAR guard: all waves done reading buf[cur^1] (step T-1)
        __builtin_amdgcn_sched_barrier(0);
        __builtin_amdgcn_s_barrier();
        __builtin_amdgcn_sched_barrier(0);
        if (T < 15) {
            STAGE_AB(cur ^ 1, (T + 1) * 64);
            asm volatile("s_waitcnt vmcnt(8)" ::: "memory");  // step-T loads (mine) done
        } else {
            asm volatile("s_waitcnt vmcnt(0)" ::: "memory");
        }
        __builtin_amdgcn_sched_barrier(0);
        __builtin_amdgcn_s_barrier();   // step-T LDS visible to all waves
        __builtin_amdgcn_sched_barrier(0);

        const short* Ac = &As[cur][0];
        const short* Bc = &Bs[cur][0];
#pragma unroll
        for (int s = 0; s < 2; s++) {
            int slot = ((s * 4 + quad) ^ (l16 & 7)) * 8;
            short8 af[4], bf[4];
#pragma unroll
            for (int i = 0; i < 4; i++)
                af[i] = *(const short8*)(Ac + (wm + i * 16 + l16) * 64 + slot);
#pragma unroll
            for (int j = 0; j < 4; j++)
                bf[j] = *(const short8*)(Bc + (wn + j * 16 + l16) * 64 + slot);
#pragma unroll
            for (int i = 0; i < 4; i++)
#pragma unroll
                for (int j = 0; j < 4; j++)
                    acc[i][j] = __builtin_amdgcn_mfma_f32_16x16x32_bf16(af[i], bf[j], acc[i][j], 0, 0, 0);
        }
    }
#undef STAGE_AB

    if (blockIdx.z == 2) {
#pragma unroll
        for (int i = 0; i < 4; i++) {
#pragma unroll
            for (int j = 0; j < 4; j++) {
                int m = bm + wm + i * 16 + quad * 4;
                int c = bn + wn + j * 16 + l16;
                int b = m >> 11, nn = m & 2047, h = c >> 6, dd = c & 63;
                short4v pk;
                pk.x = f2bs(acc[i][j][0]);
                pk.y = f2bs(acc[i][j][1]);
                pk.z = f2bs(acc[i][j][2]);
                pk.w = f2bs(acc[i][j][3]);
                *(short4v*)(vtout + ((size_t)(b * 16 + h) * 64 + dd) * 2048 + nn) = pk;
            }
        }
    } else {
        short* dst = (blockIdx.z == 0) ? qout : kout;
        float qs = (blockIdx.z == 0) ? 0.180336881f : 1.0f;  // 0.125*log2(e) folded into Q
#pragma unroll
        for (int i = 0; i < 4; i++) {
#pragma unroll
            for (int j = 0; j < 4; j++) {
#pragma unroll
                for (int r = 0; r < 4; r++) {
                    int m = bm + wm + i * 16 + quad * 4 + r;
                    int c = bn + wn + j * 16 + l16;
                    dst[((size_t)((m >> 11) * 16 + (c >> 6)) * 2048 + (m & 2047)) * 64 + (c & 63)] =
                        f2bs(acc[i][j][r] * qs);
                }
            }
        }
    }
}

// ---------------- Flash attention v4: dual-Q-stream + MFMA row-sum + zero-C ----------------
// v3 structure (single KV pass, streams A=qx / B=15-qx) with two VALU cuts (R7 counters:
// VALUBusy 55% vs MfmaUtil 21% -> VALU-bound):
//  1) denominator via MFMA-ones: racc = mfma(pf, 1.0bf16, racc) in the PV s-loop. A-layout puts
//     m=q-row=lane&31; C/D row map of racc matches oacc at equal e -> epilogue needs no shuffles.
//     Removes 64 v_add per stream-tile. Denominator sums the SAME bf16 P the numerator uses.
//  2) zero-C: first QK MFMA per tile takes block-lifetime fzero as C (D!=C legal) instead of
//     zero-initing sacc. Removes 64 v_mov per stream-tile.
__global__ __launch_bounds__(256, 2) void attn(const short* __restrict__ q,
                                               const short* __restrict__ k,
                                               const short* __restrict__ vt,
                                               float* __restrict__ out) {
    __shared__ short Ks[2][128 * 64];   // [key][d], 16B slot = chunk ^ (key&7)
    __shared__ short Vs[2][64 * 128];   // [d][key], 16B slot = (c&8)|((c^(d&7))&7)

    int tid = threadIdx.x;
    int lane = tid & 63;
    int wid = tid >> 6;
    int l32 = lane & 31;
    int half = lane >> 5;   // 0/1

    int flat = blockIdx.x;
    int xcd = flat & 7;
    int slot = flat >> 3;            // 0..63
    int bh = xcd * 8 + (slot >> 3);  // 8 (b,h) per XCD
    int qx = slot & 7;
    int b = bh >> 4, h = bh & 15;

    const short* qp = q + (size_t)(b * 16 + h) * 2048 * 64;
    const short* kp = k + (size_t)(b * 16 + h) * 2048 * 64;
    const short* vp = vt + (size_t)(b * 16 + h) * 64 * 2048;

    // K staging: 128x64. row = (tid>>3)+l*32, chunk = tid&7 (swizzled at source)
    int krow = tid >> 3;
    int ksw = ((tid & 7) ^ (krow & 7)) * 8;
    // V staging: 64x128. d = (tid>>4)+l*16, chunk16 = tid&15
    int vd = tid >> 4;
    int vc = tid & 15;
    int vsw = ((vc & 8) | ((vc ^ vd) & 7)) * 8;

#define BARRIER() asm volatile("s_barrier" ::: "memory")
#define STAGE_KV(cb, kvb) do { \
    _Pragma("unroll") for (int l = 0; l < 4; l++) { \
        const short* g = kp + (size_t)((kvb) + krow + l * 32) * 64 + ksw; \
        __builtin_amdgcn_global_load_lds((const GLOBAL_AS void*)g, \
            (LDS_AS void*)(&Ks[cb][0] + tid * 8 + l * 2048), 16, 0, 0); \
    } \
    _Pragma("unroll") for (int l = 0; l < 4; l++) { \
        const short* g = vp + (size_t)(vd + l * 16) * 2048 + (kvb) + vsw; \
        __builtin_amdgcn_global_load_lds((const GLOBAL_AS void*)g, \
            (LDS_AS void*)(&Vs[cb][0] + tid * 8 + l * 2048), 16, 0, 0); \
    } \
} while (0)

// One Q-stream tile step: S^T = K*Q^T (zero-C first step), exp2+mask, in-reg pack,
// O += P*V and racc += P*1 (denominator on the MFMA pipe).
#define STREAM_TILE(qf, qlane, oacc, racc, isdiag) do { \
    floatx16 sacc[4]; \
    __builtin_amdgcn_s_setprio(1); \
    _Pragma("unroll") for (int kb = 0; kb < 4; kb++) { \
        int key = kb * 32 + l32; \
        short8 kf = *(const short8*)(Kc + key * 64 + ((half ^ (key & 7)) * 8)); \
        sacc[kb] = __builtin_amdgcn_mfma_f32_32x32x16_bf16(kf, qf[0], fzero, 0, 0, 0); \
    } \
    _Pragma("unroll") for (int s = 1; s < 4; s++) { \
        _Pragma("unroll") for (int kb = 0; kb < 4; kb++) { \
            int key = kb * 32 + l32; \
            int c = s * 2 + half; \
            short8 kf = *(const short8*)(Kc + key * 64 + ((c ^ (key & 7)) * 8)); \
            sacc[kb] = __builtin_amdgcn_mfma_f32_32x32x16_bf16(kf, qf[s], sacc[kb], 0, 0, 0); \
        } \
    } \
    __builtin_amdgcn_s_setprio(0); \
    unsigned W0[4][4], W1[4][4]; \
    _Pragma("unroll") for (int kb = 0; kb < 4; kb++) { \
        _Pragma("unroll") for (int e = 0; e < 16; e++) { \
            float p = __builtin_amdgcn_exp2f(sacc[kb][e]); \
            if (isdiag) { \
                int key = kvb + kb * 32 + (e & 3) + 8 * (e >> 2) + 4 * half; \
                p = (key > (qlane)) ? 0.f : p; \
            } \
            sacc[kb][e] = p; \
        } \
        _Pragma("unroll") for (int g = 0; g < 4; g++) { \
            W0[kb][g] = pk2(sacc[kb][4 * g + 0], sacc[kb][4 * g + 1]); \
            W1[kb][g] = pk2(sacc[kb][4 * g + 2], sacc[kb][4 * g + 3]); \
        } \
    } \
    __builtin_amdgcn_s_setprio(1); \
    _Pragma("unroll") for (int s = 0; s < 8; s++) { \
        int kb = s >> 1; \
        int g0 = (s & 1) * 2; \
        int g1 = g0 + 1; \
        iv2 r0 = __builtin_amdgcn_permlane32_swap(W0[kb][g0], W0[kb][g1], false, false); \
        iv2 r1 = __builtin_amdgcn_permlane32_swap(W1[kb][g0], W1[kb][g1], false, false); \
        union { int4 v; short8 s8; } pu; \
        pu.v.x = r0.x; pu.v.y = r1.x; pu.v.z = r0.y; pu.v.w = r1.y; \
        short8 pf = pu.s8; \
        _Pragma("unroll") for (int nt = 0; nt < 2; nt++) { \
            int d = nt * 32 + l32; \
            int c = s * 2 + half; \
            int sl = (c & 8) | ((c ^ (d & 7)) & 7); \
            short8 vf = *(const short8*)(Vc + d * 128 + sl * 8); \
            oacc[nt] = __builtin_amdgcn_mfma_f32_32x32x16_bf16(pf, vf, oacc[nt], 0, 0, 0); \
        } \
        racc = __builtin_amdgcn_mfma_f32_32x32x16_bf16(pf, vones, racc, 0, 0, 0); \
    } \
    __builtin_amdgcn_s_setprio(0); \
} while (0)

#define EPILOG(racc, oacc, qrow_w) do { \
    float invr[16]; \
    _Pragma("unroll") for (int e = 0; e < 16; e++) invr[e] = 1.0f / racc[e]; \
    _Pragma("unroll") for (int nt = 0; nt < 2; nt++) { \
        _Pragma("unroll") for (int e = 0; e < 16; e++) { \
            int r = (e & 3) + 8 * (e >> 2) + 4 * half; \
            int nn = (qrow_w) + r; \
            out[((size_t)b * 2048 + nn) * 1024 + h * 64 + nt * 32 + l32] = oacc[nt][e] * invr[e]; \
        } \
    } \
} while (0)

    int qA = qx;        // small q-tile: consumes kv tiles 0..qA
    int qB = 15 - qx;   // large q-tile: consumes kv tiles 0..qB
    int NT = qB + 1;    // 9..16 staged tiles

    int qrowA = qA * 128 + wid * 32;
    int qrowB = qB * 128 + wid * 32;
    int qlaneA = qrowA + l32;
    int qlaneB = qrowB + l32;

    short8 qfA[4], qfB[4];
#pragma unroll
    for (int s = 0; s < 4; s++) {
        qfA[s] = *(const short8*)(qp + (size_t)qlaneA * 64 + s * 16 + half * 8);
        qfB[s] = *(const short8*)(qp + (size_t)qlaneB * 64 + s * 16 + half * 8);
    }

    // block-lifetime constants: zero C-operand and bf16 ones B-operand
    floatx16 fzero;
#pragma unroll
    for (int e = 0; e < 16; e++) fzero[e] = 0.f;
    short8 vones;
#pragma unroll
    for (int j = 0; j < 8; j++) vones[j] = (short)0x3F80;  // bf16 1.0

    floatx16 oaccA[2], oaccB[2], raccA, raccB;
#pragma unroll
    for (int nt = 0; nt < 2; nt++)
#pragma unroll
        for (int e = 0; e < 16; e++) { oaccA[nt][e] = 0.f; oaccB[nt][e] = 0.f; }
#pragma unroll
    for (int e = 0; e < 16; e++) { raccA[e] = 0.f; raccB[e] = 0.f; }

    STAGE_KV(0, 0);

    for (int t = 0; t < NT; t++) {
        int cur = t & 1;
        int kvb = t * 128;

        // WAR guard: all waves done reading buf[cur^1] (tile t-1)
        BARRIER();
        if (t + 1 < NT) {
            STAGE_KV(cur ^ 1, kvb + 128);
            asm volatile("s_waitcnt vmcnt(8)" ::: "memory");  // tile-t loads (mine) done
        } else {
            asm volatile("s_waitcnt vmcnt(0)" ::: "memory");
        }
        BARRIER();   // RAW: tile-t LDS visible to all waves

        const short* Kc = &Ks[cur][0];
        const short* Vc = &Vs[cur][0];

        if (t <= qA) {
            bool dA = (t == qA);
            STREAM_TILE(qfA, qlaneA, oaccA, raccA, dA);
        }
        {
            bool dB = (t == NT - 1);
            STREAM_TILE(qfB, qlaneB, oaccB, raccB, dB);
        }
    }

    EPILOG(raccA, oaccA, qrowA);
    EPILOG(raccB, oaccB, qrowB);

#undef STREAM_TILE
#undef EPILOG
#undef STAGE_KV
#undef BARRIER
}

extern "C" void kernel_launch(void* const* d_in, const int* in_sizes, int n_in,
                              void* d_out, int out_size, void* d_ws, size_t ws_size,
                              hipStream_t stream) {
    const float* x = (const float*)d_in[0];
    const float* Wq = (const float*)d_in[1];
    const float* Wk = (const float*)d_in[2];
    const float* Wv = (const float*)d_in[3];
    float* out = (float*)d_out;
    char* ws = (char*)d_ws;

    short* xb = (short*)ws;                          // 16 MB: [8192,1024] bf16
    short* wb = (short*)(ws + (16u << 20));          //  6 MB: [3,1024,1024] bf16
    short* qb = (short*)(ws + (22u << 20));          // 16 MB: [4,16,2048,64]
    short* kb = (short*)(ws + (38u << 20));          // 16 MB: [4,16,2048,64]
    short* vtb = (short*)(ws + (54u << 20));         // 16 MB: [4,16,64,2048]

    cast_all<<<8192 + 3 * 1024, 256, 0, stream>>>(x, Wq, Wk, Wv, xb, wb);
    qkv_gemm<<<dim3(64, 8, 3), 256, 0, stream>>>(xb, wb, qb, kb, vtb);
    attn<<<512, 256, 0, stream>>>(qb, kb, vtb, out);
}

// Round 9
// 208.739 us; speedup vs baseline: 1.1307x; 1.1307x over previous
//
#include <hip/hip_runtime.h>

typedef __attribute__((ext_vector_type(8))) short short8;
typedef __attribute__((ext_vector_type(4))) short short4v;
typedef __attribute__((ext_vector_type(4))) float floatx4;
typedef __attribute__((ext_vector_type(16))) float floatx16;
typedef __attribute__((ext_vector_type(2))) int iv2;

#define GLOBAL_AS __attribute__((address_space(1)))
#define LDS_AS __attribute__((address_space(3)))

__device__ __forceinline__ short f2bs(float f) {
    // RNE float -> bf16 (as short). Inputs finite here.
    union { float f; unsigned u; } v; v.f = f;
    unsigned r = v.u + 0x7fffu + ((v.u >> 16) & 1u);
    return (short)(r >> 16);
}

#if __has_builtin(__builtin_amdgcn_cvt_pk_bf16_f32)
typedef __attribute__((ext_vector_type(2))) __bf16 bf16x2;
__device__ __forceinline__ unsigned pk2(float a, float b) {
    union { bf16x2 v; unsigned u; } u;
    u.v = __builtin_amdgcn_cvt_pk_bf16_f32(a, b);
    return u.u;
}
#else
__device__ __forceinline__ unsigned pk2(float a, float b) {
    // round-half-up, non-negative finite inputs
    union { float f; unsigned u; } x, y; x.f = a; y.f = b;
    return ((y.u + 0x8000u) & 0xffff0000u) | ((x.u + 0x8000u) >> 16);
}
#endif

// ---------------- fused cast fp32 -> bf16 (x + Wq + Wk + Wv) ----------------
__global__ __launch_bounds__(256) void cast_all(const float* __restrict__ x,
                                                const float* __restrict__ Wq,
                                                const float* __restrict__ Wk,
                                                const float* __restrict__ Wv,
                                                short* __restrict__ xb,
                                                short* __restrict__ wb) {
    int b = blockIdx.x;
    int t = threadIdx.x;
    const float* src;
    short* dst;
    int idx;
    if (b < 8192) {
        src = x; dst = xb; idx = b * 1024 + t * 4;
    } else {
        int r = b - 8192;
        int wz = r >> 10;
        src = (wz == 0) ? Wq : (wz == 1) ? Wk : Wv;
        dst = wb + wz * (1 << 20);
        idx = (r & 1023) * 1024 + t * 4;
    }
    float4 v = *(const float4*)(src + idx);
    short4v o;
    o.x = f2bs(v.x); o.y = f2bs(v.y); o.z = f2bs(v.z); o.w = f2bs(v.w);
    *(short4v*)(dst + idx) = o;
}

// ---------------- QKV GEMM v3: R4-proven 128x128 dbuf, counted vmcnt ----------------
__global__ __launch_bounds__(256) void qkv_gemm(const short* __restrict__ xb,
                                                const short* __restrict__ wb,
                                                short* __restrict__ qout,
                                                short* __restrict__ kout,
                                                short* __restrict__ vtout) {
    __shared__ short As[2][128 * 64];  // [m][k], 16B chunks XOR-swizzled: slot = chunk ^ (row&7)
    __shared__ short Bs[2][128 * 64];
    const int K = 1024;
    int tid = threadIdx.x;
    int lane = tid & 63;
    int wid = tid >> 6;
    int quad = lane >> 4;
    int l16 = lane & 15;
    int wm = (wid >> 1) * 64;
    int wn = (wid & 1) * 64;
    int bm = blockIdx.x * 128;
    int bn = blockIdx.y * 128;
    const short* W = wb + (size_t)blockIdx.z * K * 1024;

    floatx4 acc[4][4];
#pragma unroll
    for (int i = 0; i < 4; i++)
#pragma unroll
        for (int j = 0; j < 4; j++) acc[i][j] = (floatx4){0.f, 0.f, 0.f, 0.f};

    int srow = tid >> 3;
    int ssw = ((tid & 7) ^ (srow & 7)) * 8;

#define STAGE_AB(cb, kk) do { \
    _Pragma("unroll") for (int l = 0; l < 4; l++) { \
        const short* g = xb + (size_t)(bm + srow + l * 32) * K + (kk) + ssw; \
        __builtin_amdgcn_global_load_lds((const GLOBAL_AS void*)g, \
            (LDS_AS void*)(&As[cb][0] + tid * 8 + l * 2048), 16, 0, 0); \
    } \
    _Pragma("unroll") for (int l = 0; l < 4; l++) { \
        const short* g = W + (size_t)(bn + srow + l * 32) * K + (kk) + ssw; \
        __builtin_amdgcn_global_load_lds((const GLOBAL_AS void*)g, \
            (LDS_AS void*)(&Bs[cb][0] + tid * 8 + l * 2048), 16, 0, 0); \
    } \
} while (0)

    STAGE_AB(0, 0);

    for (int T = 0; T < 16; T++) {
        int cur = T & 1;
        // WAR guard: all waves done reading buf[cur^1] (step T-1)
        __builtin_amdgcn_sched_barrier(0);
        __builtin_amdgcn_s_barrier();
        __builtin_amdgcn_sched_barrier(0);
        if (T < 15) {
            STAGE_AB(cur ^ 1, (T + 1) * 64);
            asm volatile("s_waitcnt vmcnt(8)" ::: "memory");  // step-T loads (mine) done
        } else {
            asm volatile("s_waitcnt vmcnt(0)" ::: "memory");
        }
        __builtin_amdgcn_sched_barrier(0);
        __builtin_amdgcn_s_barrier();   // step-T LDS visible to all waves
        __builtin_amdgcn_sched_barrier(0);

        const short* Ac = &As[cur][0];
        const short* Bc = &Bs[cur][0];
#pragma unroll
        for (int s = 0; s < 2; s++) {
            int slot = ((s * 4 + quad) ^ (l16 & 7)) * 8;
            short8 af[4], bf[4];
#pragma unroll
            for (int i = 0; i < 4; i++)
                af[i] = *(const short8*)(Ac + (wm + i * 16 + l16) * 64 + slot);
#pragma unroll
            for (int j = 0; j < 4; j++)
                bf[j] = *(const short8*)(Bc + (wn + j * 16 + l16) * 64 + slot);
#pragma unroll
            for (int i = 0; i < 4; i++)
#pragma unroll
                for (int j = 0; j < 4; j++)
                    acc[i][j] = __builtin_amdgcn_mfma_f32_16x16x32_bf16(af[i], bf[j], acc[i][j], 0, 0, 0);
        }
    }
#undef STAGE_AB

    if (blockIdx.z == 2) {
#pragma unroll
        for (int i = 0; i < 4; i++) {
#pragma unroll
            for (int j = 0; j < 4; j++) {
                int m = bm + wm + i * 16 + quad * 4;
                int c = bn + wn + j * 16 + l16;
                int b = m >> 11, nn = m & 2047, h = c >> 6, dd = c & 63;
                short4v pk;
                pk.x = f2bs(acc[i][j][0]);
                pk.y = f2bs(acc[i][j][1]);
                pk.z = f2bs(acc[i][j][2]);
                pk.w = f2bs(acc[i][j][3]);
                *(short4v*)(vtout + ((size_t)(b * 16 + h) * 64 + dd) * 2048 + nn) = pk;
            }
        }
    } else {
        short* dst = (blockIdx.z == 0) ? qout : kout;
        float qs = (blockIdx.z == 0) ? 0.180336881f : 1.0f;  // 0.125*log2(e) folded into Q
#pragma unroll
        for (int i = 0; i < 4; i++) {
#pragma unroll
            for (int j = 0; j < 4; j++) {
#pragma unroll
                for (int r = 0; r < 4; r++) {
                    int m = bm + wm + i * 16 + quad * 4 + r;
                    int c = bn + wn + j * 16 + l16;
                    dst[((size_t)((m >> 11) * 16 + (c >> 6)) * 2048 + (m & 2047)) * 64 + (c & 63)] =
                        f2bs(acc[i][j][r] * qs);
                }
            }
        }
    }
}

// ---------------- Flash attention v3 (R7 proven): dual-Q-stream single KV pass ----------------
// Streams A=qx / B=15-qx share one pass over KV tiles 0..(15-qx); A consumes t<=qA, B always.
// In-register P via permlane32_swap; K/V double-buffered, counted vmcnt(8); setprio on MFMA
// clusters. Measured R7: 71 us, VGPR 108, no spill. (R8's MFMA-rowsum variant spilled at the
// 128-VGPR cap -> reverted; any future change must fit in ~20 spare VGPRs.)
__global__ __launch_bounds__(256, 2) void attn(const short* __restrict__ q,
                                               const short* __restrict__ k,
                                               const short* __restrict__ vt,
                                               float* __restrict__ out) {
    __shared__ short Ks[2][128 * 64];   // [key][d], 16B slot = chunk ^ (key&7)
    __shared__ short Vs[2][64 * 128];   // [d][key], 16B slot = (c&8)|((c^(d&7))&7)

    int tid = threadIdx.x;
    int lane = tid & 63;
    int wid = tid >> 6;
    int l32 = lane & 31;
    int half = lane >> 5;   // 0/1

    int flat = blockIdx.x;
    int xcd = flat & 7;
    int slot = flat >> 3;            // 0..63
    int bh = xcd * 8 + (slot >> 3);  // 8 (b,h) per XCD
    int qx = slot & 7;
    int b = bh >> 4, h = bh & 15;

    const short* qp = q + (size_t)(b * 16 + h) * 2048 * 64;
    const short* kp = k + (size_t)(b * 16 + h) * 2048 * 64;
    const short* vp = vt + (size_t)(b * 16 + h) * 64 * 2048;

    // K staging: 128x64. row = (tid>>3)+l*32, chunk = tid&7 (swizzled at source)
    int krow = tid >> 3;
    int ksw = ((tid & 7) ^ (krow & 7)) * 8;
    // V staging: 64x128. d = (tid>>4)+l*16, chunk16 = tid&15
    int vd = tid >> 4;
    int vc = tid & 15;
    int vsw = ((vc & 8) | ((vc ^ vd) & 7)) * 8;

#define BARRIER() asm volatile("s_barrier" ::: "memory")
#define STAGE_KV(cb, kvb) do { \
    _Pragma("unroll") for (int l = 0; l < 4; l++) { \
        const short* g = kp + (size_t)((kvb) + krow + l * 32) * 64 + ksw; \
        __builtin_amdgcn_global_load_lds((const GLOBAL_AS void*)g, \
            (LDS_AS void*)(&Ks[cb][0] + tid * 8 + l * 2048), 16, 0, 0); \
    } \
    _Pragma("unroll") for (int l = 0; l < 4; l++) { \
        const short* g = vp + (size_t)(vd + l * 16) * 2048 + (kvb) + vsw; \
        __builtin_amdgcn_global_load_lds((const GLOBAL_AS void*)g, \
            (LDS_AS void*)(&Vs[cb][0] + tid * 8 + l * 2048), 16, 0, 0); \
    } \
} while (0)

// One Q-stream tile step: S^T = K*Q^T, exp2+mask+row-sum, in-reg pack, O += P*V.
#define STREAM_TILE(qf, qlane, oacc, rs, isdiag) do { \
    floatx16 sacc[4]; \
    _Pragma("unroll") for (int kb = 0; kb < 4; kb++) \
    _Pragma("unroll") for (int e = 0; e < 16; e++) sacc[kb][e] = 0.f; \
    __builtin_amdgcn_s_setprio(1); \
    _Pragma("unroll") for (int s = 0; s < 4; s++) { \
        _Pragma("unroll") for (int kb = 0; kb < 4; kb++) { \
            int key = kb * 32 + l32; \
            int c = s * 2 + half; \
            short8 kf = *(const short8*)(Kc + key * 64 + ((c ^ (key & 7)) * 8)); \
            sacc[kb] = __builtin_amdgcn_mfma_f32_32x32x16_bf16(kf, qf[s], sacc[kb], 0, 0, 0); \
        } \
    } \
    __builtin_amdgcn_s_setprio(0); \
    unsigned W0[4][4], W1[4][4]; \
    _Pragma("unroll") for (int kb = 0; kb < 4; kb++) { \
        _Pragma("unroll") for (int e = 0; e < 16; e++) { \
            float p = __builtin_amdgcn_exp2f(sacc[kb][e]); \
            if (isdiag) { \
                int key = kvb + kb * 32 + (e & 3) + 8 * (e >> 2) + 4 * half; \
                p = (key > (qlane)) ? 0.f : p; \
            } \
            sacc[kb][e] = p; \
            rs += p; \
        } \
        _Pragma("unroll") for (int g = 0; g < 4; g++) { \
            W0[kb][g] = pk2(sacc[kb][4 * g + 0], sacc[kb][4 * g + 1]); \
            W1[kb][g] = pk2(sacc[kb][4 * g + 2], sacc[kb][4 * g + 3]); \
        } \
    } \
    __builtin_amdgcn_s_setprio(1); \
    _Pragma("unroll") for (int s = 0; s < 8; s++) { \
        int kb = s >> 1; \
        int g0 = (s & 1) * 2; \
        int g1 = g0 + 1; \
        iv2 r0 = __builtin_amdgcn_permlane32_swap(W0[kb][g0], W0[kb][g1], false, false); \
        iv2 r1 = __builtin_amdgcn_permlane32_swap(W1[kb][g0], W1[kb][g1], false, false); \
        union { int4 v; short8 s8; } pu; \
        pu.v.x = r0.x; pu.v.y = r1.x; pu.v.z = r0.y; pu.v.w = r1.y; \
        short8 pf = pu.s8; \
        _Pragma("unroll") for (int nt = 0; nt < 2; nt++) { \
            int d = nt * 32 + l32; \
            int c = s * 2 + half; \
            int sl = (c & 8) | ((c ^ (d & 7)) & 7); \
            short8 vf = *(const short8*)(Vc + d * 128 + sl * 8); \
            oacc[nt] = __builtin_amdgcn_mfma_f32_32x32x16_bf16(pf, vf, oacc[nt], 0, 0, 0); \
        } \
    } \
    __builtin_amdgcn_s_setprio(0); \
} while (0)

#define EPILOG(rs, oacc, qrow_w) do { \
    float tot = (rs) + __shfl_xor((rs), 32); \
    float inv = 1.0f / tot; \
    float invr[16]; \
    _Pragma("unroll") for (int e = 0; e < 16; e++) \
        invr[e] = __shfl(inv, (e & 3) + 8 * (e >> 2) + 4 * half); \
    _Pragma("unroll") for (int nt = 0; nt < 2; nt++) { \
        _Pragma("unroll") for (int e = 0; e < 16; e++) { \
            int r = (e & 3) + 8 * (e >> 2) + 4 * half; \
            int nn = (qrow_w) + r; \
            out[((size_t)b * 2048 + nn) * 1024 + h * 64 + nt * 32 + l32] = oacc[nt][e] * invr[e]; \
        } \
    } \
} while (0)

    int qA = qx;        // small q-tile: consumes kv tiles 0..qA
    int qB = 15 - qx;   // large q-tile: consumes kv tiles 0..qB
    int NT = qB + 1;    // 9..16 staged tiles (was 17)

    int qrowA = qA * 128 + wid * 32;
    int qrowB = qB * 128 + wid * 32;
    int qlaneA = qrowA + l32;
    int qlaneB = qrowB + l32;

    short8 qfA[4], qfB[4];
#pragma unroll
    for (int s = 0; s < 4; s++) {
        qfA[s] = *(const short8*)(qp + (size_t)qlaneA * 64 + s * 16 + half * 8);
        qfB[s] = *(const short8*)(qp + (size_t)qlaneB * 64 + s * 16 + half * 8);
    }

    floatx16 oaccA[2], oaccB[2];
#pragma unroll
    for (int nt = 0; nt < 2; nt++)
#pragma unroll
        for (int e = 0; e < 16; e++) { oaccA[nt][e] = 0.f; oaccB[nt][e] = 0.f; }
    float rsA = 0.f, rsB = 0.f;

    STAGE_KV(0, 0);

    for (int t = 0; t < NT; t++) {
        int cur = t & 1;
        int kvb = t * 128;

        // WAR guard: all waves done reading buf[cur^1] (tile t-1)
        BARRIER();
        if (t + 1 < NT) {
            STAGE_KV(cur ^ 1, kvb + 128);
            asm volatile("s_waitcnt vmcnt(8)" ::: "memory");  // tile-t loads (mine) done
        } else {
            asm volatile("s_waitcnt vmcnt(0)" ::: "memory");
        }
        BARRIER();   // RAW: tile-t LDS visible to all waves

        const short* Kc = &Ks[cur][0];
        const short* Vc = &Vs[cur][0];

        if (t <= qA) {
            bool dA = (t == qA);
            STREAM_TILE(qfA, qlaneA, oaccA, rsA, dA);
        }
        {
            bool dB = (t == NT - 1);
            STREAM_TILE(qfB, qlaneB, oaccB, rsB, dB);
        }
    }

    EPILOG(rsA, oaccA, qrowA);
    EPILOG(rsB, oaccB, qrowB);

#undef STREAM_TILE
#undef EPILOG
#undef STAGE_KV
#undef BARRIER
}

extern "C" void kernel_launch(void* const* d_in, const int* in_sizes, int n_in,
                              void* d_out, int out_size, void* d_ws, size_t ws_size,
                              hipStream_t stream) {
    const float* x = (const float*)d_in[0];
    const float* Wq = (const float*)d_in[1];
    const float* Wk = (const float*)d_in[2];
    const float* Wv = (const float*)d_in[3];
    float* out = (float*)d_out;
    char* ws = (char*)d_ws;

    short* xb = (short*)ws;                          // 16 MB: [8192,1024] bf16
    short* wb = (short*)(ws + (16u << 20));          //  6 MB: [3,1024,1024] bf16
    short* qb = (short*)(ws + (22u << 20));          // 16 MB: [4,16,2048,64]
    short* kb = (short*)(ws + (38u << 20));          // 16 MB: [4,16,2048,64]
    short* vtb = (short*)(ws + (54u << 20));         // 16 MB: [4,16,64,2048]

    cast_all<<<8192 + 3 * 1024, 256, 0, stream>>>(x, Wq, Wk, Wv, xb, wb);
    qkv_gemm<<<dim3(64, 8, 3), 256, 0, stream>>>(xb, wb, qb, kb, vtb);
    attn<<<512, 256, 0, stream>>>(qb, kb, vtb, out);
}